// Round 5
// baseline (1190.252 us; speedup 1.0000x reference)
//
#include <hip/hip_runtime.h>
#include <hip/hip_bf16.h>
#include <math.h>

typedef __attribute__((ext_vector_type(8))) short bf16x8;
typedef __attribute__((ext_vector_type(4))) float f32x4;

__device__ __forceinline__ unsigned short f2b(float f) {
  unsigned u = __float_as_uint(f);
  unsigned r = (u + 0x7FFF + ((u >> 16) & 1)) >> 16;
  return (unsigned short)r;
}

__device__ __forceinline__ void async16(const void* g, void* l) {
  __builtin_amdgcn_global_load_lds(
      (const __attribute__((address_space(1))) unsigned int*)(g),
      (__attribute__((address_space(3))) unsigned int*)(l), 16, 0, 0);
}

// Sum across the 16 lanes of a DPP row (lanes 16k..16k+15) via row_ror.
__device__ __forceinline__ float rowsum16(float x) {
  x += __int_as_float(__builtin_amdgcn_update_dpp(0, __float_as_int(x), 0x121, 0xF, 0xF, false));
  x += __int_as_float(__builtin_amdgcn_update_dpp(0, __float_as_int(x), 0x122, 0xF, 0xF, false));
  x += __int_as_float(__builtin_amdgcn_update_dpp(0, __float_as_int(x), 0x124, 0xF, 0xF, false));
  x += __int_as_float(__builtin_amdgcn_update_dpp(0, __float_as_int(x), 0x128, 0xF, 0xF, false));
  return x;
}

// ---------------------------------------------------------------------------
// fp32 -> bf16 converts: x,R,K,V fused (R/K/V into one concatenated 3072x2048).
// ---------------------------------------------------------------------------
__global__ __launch_bounds__(256) void cvt4_kernel(
    const float* __restrict__ x, const float* __restrict__ R,
    const float* __restrict__ K, const float* __restrict__ V,
    unsigned short* __restrict__ xb, unsigned short* __restrict__ RKVb)
{
  const int bid = blockIdx.x;
  const float* s; unsigned short* d; int i;
  if (bid < 8192)       { s = x; d = xb; i = bid * 256 + threadIdx.x; }
  else if (bid < 12288) { s = R; d = RKVb; i = (bid - 8192) * 256 + threadIdx.x; }
  else if (bid < 13312) { s = K; d = RKVb + 2048 * 2048; i = (bid - 12288) * 256 + threadIdx.x; }
  else                  { s = V; d = RKVb + 2560 * 2048; i = (bid - 13312) * 256 + threadIdx.x; }
  float4 v = ((const float4*)s)[i];
  ushort4 o;
  o.x = f2b(v.x); o.y = f2b(v.y); o.z = f2b(v.z); o.w = f2b(v.w);
  ((ushort4*)d)[i] = o;
}

__global__ __launch_bounds__(256) void cvt_bf16(
    const float* __restrict__ s, unsigned short* __restrict__ d, int n4)
{
  int i = blockIdx.x * 256 + threadIdx.x;
  if (i < n4) {
    float4 v = ((const float4*)s)[i];
    ushort4 o;
    o.x = f2b(v.x); o.y = f2b(v.y); o.z = f2b(v.z); o.w = f2b(v.w);
    ((ushort4*)d)[i] = o;
  }
}

// ---------------------------------------------------------------------------
// Transposed convert: out[n*ors + k] = bf16(in[k*Nd + n]).
// ---------------------------------------------------------------------------
__global__ __launch_bounds__(256) void tcvt_kernel(
    const float* __restrict__ in, unsigned short* __restrict__ out,
    int Kd, int Nd, int ors)
{
  __shared__ unsigned short tile[64][65];
  const int tx = threadIdx.x & 63, ty = threadIdx.x >> 6;
  const int n0 = blockIdx.x * 64, k0 = blockIdx.y * 64;
  #pragma unroll
  for (int j = 0; j < 16; ++j) {
    const int k = k0 + j * 4 + ty;
    const int n = n0 + tx;
    unsigned short v = 0;
    if (k < Kd && n < Nd) v = f2b(in[(size_t)k * Nd + n]);
    tile[j * 4 + ty][tx] = v;
  }
  __syncthreads();
  #pragma unroll
  for (int j = 0; j < 16; ++j) {
    const int n = n0 + j * 4 + ty;
    const int k = k0 + tx;
    if (n < Nd && k < Kd) out[(size_t)n * ors + k] = tile[tx][j * 4 + ty];
  }
}

// ---------------------------------------------------------------------------
// bf16 MFMA GEMM: C[M,N] = A[M,K] @ B[N,K]^T (+bias). 128x128 tile, BK=32.
// ---------------------------------------------------------------------------
template<int OUTBF16, int ACT>
__global__ __launch_bounds__(256) void gemm_mfma(
    const unsigned short* __restrict__ A, int lda,
    const unsigned short* __restrict__ B, int ldb,
    const float* __restrict__ bias, void* __restrict__ Cv, int ldc,
    int M, int N, int K)
{
  __shared__ __align__(16) unsigned short As[128 * 32];
  __shared__ __align__(16) unsigned short Bs[128 * 32];
  const int tid = threadIdx.x;
  const int w = tid >> 6, lane = tid & 63;
  const int wr = (w >> 1) * 64, wc = (w & 1) * 64;
  const int row0 = blockIdx.y * 128, col0 = blockIdx.x * 128;

  f32x4 acc[4][4];
  #pragma unroll
  for (int i = 0; i < 4; ++i)
    #pragma unroll
    for (int j = 0; j < 4; ++j)
      acc[i][j] = (f32x4){0.f, 0.f, 0.f, 0.f};

  const int srow = w * 32 + (lane >> 2);
  const int scol = (lane & 3) * 8;
  const int brow0 = (col0 + srow < N) ? (col0 + srow) : 0;
  const int brow1 = (col0 + srow + 16 < N) ? (col0 + srow + 16) : 0;
  const unsigned short* gA0 = A + (size_t)(row0 + srow) * lda + scol;
  const unsigned short* gA1 = gA0 + (size_t)16 * lda;
  const unsigned short* gB0 = B + (size_t)brow0 * ldb + scol;
  const unsigned short* gB1 = B + (size_t)brow1 * ldb + scol;
  unsigned short* lA0 = As + w * 1024;
  unsigned short* lA1 = As + w * 1024 + 512;
  unsigned short* lB0 = Bs + w * 1024;
  unsigned short* lB1 = Bs + w * 1024 + 512;

  const int m16 = lane & 15;
  const int q8  = (lane >> 4) * 8;

  for (int k0 = 0; k0 < K; k0 += 32) {
    async16(gA0, lA0);
    async16(gA1, lA1);
    async16(gB0, lB0);
    async16(gB1, lB1);
    gA0 += 32; gA1 += 32; gB0 += 32; gB1 += 32;
    __syncthreads();
    bf16x8 af[4], bfr[4];
    #pragma unroll
    for (int i = 0; i < 4; ++i) {
      af[i]  = *(const bf16x8*)(As + (wr + i * 16 + m16) * 32 + q8);
      bfr[i] = *(const bf16x8*)(Bs + (wc + i * 16 + m16) * 32 + q8);
    }
    #pragma unroll
    for (int i = 0; i < 4; ++i)
      #pragma unroll
      for (int j = 0; j < 4; ++j)
        acc[i][j] = __builtin_amdgcn_mfma_f32_16x16x32_bf16(af[i], bfr[j], acc[i][j], 0, 0, 0);
    __syncthreads();
  }

  #pragma unroll
  for (int j = 0; j < 4; ++j) {
    const int c_ = col0 + wc + j * 16 + (lane & 15);
    if (c_ < N) {
      const float bv = bias ? bias[c_] : 0.f;
      #pragma unroll
      for (int i = 0; i < 4; ++i) {
        const int r_ = row0 + wr + i * 16 + (lane >> 4) * 4;
        #pragma unroll
        for (int t4 = 0; t4 < 4; ++t4) {
          float v = acc[i][j][t4] + bv;
          if (ACT == 2 && c_ < 64) v = tanhf(v);
          if (OUTBF16)
            ((unsigned short*)Cv)[(size_t)(r_ + t4) * ldc + c_] = f2b(v);
          else
            ((float*)Cv)[(size_t)(r_ + t4) * ldc + c_] = v;
        }
      }
    }
  }
}

// ---------------------------------------------------------------------------
// Merged R|K|V projection GEMM (concatenated 3072x2048 weight).
// ---------------------------------------------------------------------------
__global__ __launch_bounds__(256) void gemm_rkv(
    const unsigned short* __restrict__ A, const unsigned short* __restrict__ B,
    const float* __restrict__ Rb_, const float* __restrict__ Kb_,
    const float* __restrict__ Vb_,
    float* __restrict__ Cr, float* __restrict__ Ck, float* __restrict__ Cvv)
{
  __shared__ __align__(16) unsigned short As[128 * 32];
  __shared__ __align__(16) unsigned short Bs[128 * 32];
  const int tid = threadIdx.x;
  const int w = tid >> 6, lane = tid & 63;
  const int wr = (w >> 1) * 64, wc = (w & 1) * 64;
  const int row0 = blockIdx.y * 128, col0 = blockIdx.x * 128;

  float* Cd; int ldc, cbase; const float* bias;
  if (col0 < 2048)      { Cd = Cr;  ldc = 2048; cbase = col0;        bias = Rb_; }
  else if (col0 < 2560) { Cd = Ck;  ldc = 512;  cbase = col0 - 2048; bias = Kb_; }
  else                  { Cd = Cvv; ldc = 512;  cbase = col0 - 2560; bias = Vb_; }

  f32x4 acc[4][4];
  #pragma unroll
  for (int i = 0; i < 4; ++i)
    #pragma unroll
    for (int j = 0; j < 4; ++j)
      acc[i][j] = (f32x4){0.f, 0.f, 0.f, 0.f};

  const int srow = w * 32 + (lane >> 2);
  const int scol = (lane & 3) * 8;
  const unsigned short* gA0 = A + (size_t)(row0 + srow) * 2048 + scol;
  const unsigned short* gA1 = gA0 + (size_t)16 * 2048;
  const unsigned short* gB0 = B + (size_t)(col0 + srow) * 2048 + scol;
  const unsigned short* gB1 = gB0 + (size_t)16 * 2048;
  unsigned short* lA0 = As + w * 1024;
  unsigned short* lA1 = As + w * 1024 + 512;
  unsigned short* lB0 = Bs + w * 1024;
  unsigned short* lB1 = Bs + w * 1024 + 512;

  const int m16 = lane & 15;
  const int q8  = (lane >> 4) * 8;

  for (int k0 = 0; k0 < 2048; k0 += 32) {
    async16(gA0, lA0);
    async16(gA1, lA1);
    async16(gB0, lB0);
    async16(gB1, lB1);
    gA0 += 32; gA1 += 32; gB0 += 32; gB1 += 32;
    __syncthreads();
    bf16x8 af[4], bfr[4];
    #pragma unroll
    for (int i = 0; i < 4; ++i) {
      af[i]  = *(const bf16x8*)(As + (wr + i * 16 + m16) * 32 + q8);
      bfr[i] = *(const bf16x8*)(Bs + (wc + i * 16 + m16) * 32 + q8);
    }
    #pragma unroll
    for (int i = 0; i < 4; ++i)
      #pragma unroll
      for (int j = 0; j < 4; ++j)
        acc[i][j] = __builtin_amdgcn_mfma_f32_16x16x32_bf16(af[i], bfr[j], acc[i][j], 0, 0, 0);
    __syncthreads();
  }

  #pragma unroll
  for (int j = 0; j < 4; ++j) {
    const int c_ = cbase + wc + j * 16 + (lane & 15);
    const float bv = bias[c_];
    #pragma unroll
    for (int i = 0; i < 4; ++i) {
      const int r_ = row0 + wr + i * 16 + (lane >> 4) * 4;
      #pragma unroll
      for (int t4 = 0; t4 < 4; ++t4)
        Cd[(size_t)(r_ + t4) * ldc + c_] = acc[i][j][t4] + bv;
    }
  }
}

// ---------------------------------------------------------------------------
// Elementwise prep (unchanged).
// ---------------------------------------------------------------------------
__global__ __launch_bounds__(256) void prep_kernel(
    const float* __restrict__ k_buf, const float* __restrict__ v_buf,
    float* wt_decay, const float* __restrict__ at, float* vt_vf,
    const float* __restrict__ v_first,
    const float* __restrict__ w0, const float* __restrict__ a0,
    const float* __restrict__ v0, const float* __restrict__ k_k,
    const float* __restrict__ k_a,
    float* __restrict__ kf, float* __restrict__ aaq, float* __restrict__ bbq)
{
  const int row = blockIdx.x;
  const int tid = threadIdx.x;
  const int c0 = tid << 3;
  const int h = tid >> 3;
  const int kvoff = (h >> 2) << 6;
  const size_t base = (size_t)row * 2048;
  const size_t kvrow = (size_t)row * 512;
  float kr[8], kkr[8];
  float ss = 0.f;
  #pragma unroll
  for (int e = 0; e < 8; ++e) {
    const int c = c0 + e;
    const float kv = k_buf[kvrow + kvoff + (c & 63)];
    kr[e] = kv;
    const float t = kv * k_k[c];
    kkr[e] = t;
    ss = fmaf(t, t, ss);
  }
  ss += __shfl_xor(ss, 1);
  ss += __shfl_xor(ss, 2);
  ss += __shfl_xor(ss, 4);
  const float inv = 1.f / fmaxf(sqrtf(ss), 1e-12f);
  #pragma unroll
  for (int e = 0; e < 8; ++e) {
    const int c = c0 + e;
    const size_t idx = base + c;
    const float kk = kkr[e] * inv;
    const float a = 1.f / (1.f + expf(-(a0[c] + at[idx])));
    const float u = w0[c] + wt_decay[idx];
    const float sig_u = 1.f / (1.f + expf(-u));
    wt_decay[idx] = expf(-0.5488116360940264f * sig_u);
    kf[idx] = kr[e] * fmaf(a - 1.f, k_a[c], 1.f);
    const float vr = v_buf[kvrow + kvoff + (c & 63)];
    const float sv = 1.f / (1.f + expf(-(v0[c] + vt_vf[idx])));
    vt_vf[idx] = vr + (v_first[idx] - vr) * sv;
    aaq[idx] = -kk;
    bbq[idx] = kk * a;
  }
}

// ---------------------------------------------------------------------------
// RWKV-7 scan — row-parallel, barrier-free. 2048 independent waves.
// XCD-swizzled block mapping: beta = x + 8m + 128s -> bh = x*16+m, g = 4s+widx,
// so all 4 blocks serving one bh share (beta mod 8) == same XCD -> the 16-way
// replicated vector-stream reads hit that XCD's L2 instead of HBM.
// Prefetch depth 4 (register pipeline) to double loads in flight.
// ---------------------------------------------------------------------------
__global__ __launch_bounds__(256) void scan_kernel(
    const float* __restrict__ rB, const float* __restrict__ dB,
    const float* __restrict__ kB, const float* __restrict__ vB,
    const float* __restrict__ aB, const float* __restrict__ bB,
    const float* __restrict__ state, float* __restrict__ y)
{
  const int tid = threadIdx.x;
  const int beta = blockIdx.x;
  const int bh = ((beta & 7) << 4) | ((beta >> 3) & 15);
  const int g = ((beta >> 7) << 2) | (tid >> 6);
  const int b = bh >> 5, h = bh & 31;
  const int lane = tid & 63;
  const int row = (g << 2) + (lane >> 4);
  const int colg = lane & 15;

  float4 S = *(const float4*)(state + (size_t)bh * 4096 + row * 64 + (colg << 2));

  const unsigned cb = (unsigned)((b * 1024) * 2048 + h * 64);
  unsigned vo = cb + (colg << 2);   // vector streams (float index)
  unsigned vs = cb + row;           // v-stream / y-store index

  float4 af[4], df[4], bf[4], kq[4], rq[4]; float vq[4];
  #pragma unroll
  for (int j = 0; j < 4; ++j) {
    af[j] = *(const float4*)(aB + vo + j * 2048);
    df[j] = *(const float4*)(dB + vo + j * 2048);
    bf[j] = *(const float4*)(bB + vo + j * 2048);
    kq[j] = *(const float4*)(kB + vo + j * 2048);
    rq[j] = *(const float4*)(rB + vo + j * 2048);
    vq[j] = vB[vs + (size_t)j * 2048];
  }

  unsigned pf = vo + 4 * 2048;
  unsigned ps = vs + 4 * 2048;
  unsigned yo = vs;

  #pragma unroll 4
  for (int t = 0; t < 1024; ++t) {
    const int p = t & 3;
    const float4 av = af[p], dv = df[p], bv = bf[p], kv = kq[p], rv = rq[p];
    const float vv = vq[p];
    if (t < 1020) {   // prefetch step t+4 into the slot just consumed
      af[p] = *(const float4*)(aB + pf);
      df[p] = *(const float4*)(dB + pf);
      bf[p] = *(const float4*)(bB + pf);
      kq[p] = *(const float4*)(kB + pf);
      rq[p] = *(const float4*)(rB + pf);
      vq[p] = vB[ps];
      pf += 2048; ps += 2048;
    }
    float t0 = fmaf(S.y, av.y, S.x * av.x);
    t0 = fmaf(S.z, av.z, t0);
    t0 = fmaf(S.w, av.w, t0);
    const float sa = rowsum16(t0);
    S.x = fmaf(S.x, dv.x, fmaf(sa, bv.x, vv * kv.x));
    S.y = fmaf(S.y, dv.y, fmaf(sa, bv.y, vv * kv.y));
    S.z = fmaf(S.z, dv.z, fmaf(sa, bv.z, vv * kv.z));
    S.w = fmaf(S.w, dv.w, fmaf(sa, bv.w, vv * kv.w));
    float t1 = fmaf(S.y, rv.y, S.x * rv.x);
    t1 = fmaf(S.z, rv.z, t1);
    t1 = fmaf(S.w, rv.w, t1);
    const float yv = rowsum16(t1);
    if (colg == 0) y[yo] = yv;
    yo += 2048;
  }
}

// ---------------------------------------------------------------------------
// GroupNorm pass A: partial sums per (bh, seg of 128 t-rows) -> part[blk].
// ---------------------------------------------------------------------------
__global__ __launch_bounds__(256) void gsum_kernel(
    const float* __restrict__ y, float* __restrict__ part)
{
  const int blk = blockIdx.x;        // bh*8 + seg
  const int bh = blk >> 3, seg = blk & 7;
  const int b = bh >> 5, h = bh & 31;
  const int tid = threadIdx.x;
  const size_t base = ((size_t)(b * 1024 + seg * 128)) * 2048 + h * 64;
  float s = 0.f, ss = 0.f;
  for (int i = tid; i < 8192; i += 256) {
    const int t = i >> 6, n = i & 63;
    const float v = y[base + (size_t)t * 2048 + n];
    s += v;
    ss = fmaf(v, v, ss);
  }
  #pragma unroll
  for (int o = 1; o < 64; o <<= 1) {
    s  += __shfl_xor(s, o);
    ss += __shfl_xor(ss, o);
  }
  __shared__ float red[8];
  const int wid = tid >> 6;
  if ((tid & 63) == 0) { red[wid] = s; red[4 + wid] = ss; }
  __syncthreads();
  if (tid == 0) {
    const float st  = red[0] + red[1] + red[2] + red[3];
    const float sst = red[4] + red[5] + red[6] + red[7];
    ((float2*)part)[blk] = make_float2(st, sst);
  }
}

// ---------------------------------------------------------------------------
// GroupNorm pass B + bonus: per-(b,t) row, writes xx in bf16.
// ---------------------------------------------------------------------------
__global__ __launch_bounds__(256) void gapply_kernel(
    const float* __restrict__ y, const float* __restrict__ rB,
    const float* __restrict__ kf, const float* __restrict__ vf,
    const float* __restrict__ part, const float* __restrict__ r_k,
    const float* __restrict__ ln_w, const float* __restrict__ ln_b,
    unsigned short* __restrict__ xxb)
{
  const int row = blockIdx.x;        // b*1024 + t
  const int b = row >> 10;
  const int tid = threadIdx.x;
  const int h = tid >> 3;
  const int bh = b * 32 + h;
  float s = 0.f, ss = 0.f;
  #pragma unroll
  for (int j = 0; j < 8; ++j) {
    const float2 pr = ((const float2*)part)[(bh << 3) + j];
    s += pr.x; ss += pr.y;
  }
  const float mean = s * (1.f / 65536.f);
  const float rstd = rsqrtf(ss * (1.f / 65536.f) - mean * mean + 0.00064f);
  const int c0 = tid << 3;
  const size_t base = (size_t)row * 2048 + c0;
  float yv[8], vv[8];
  float p = 0.f;
  #pragma unroll
  for (int e = 0; e < 8; ++e) {
    yv[e] = y[base + e];
    vv[e] = vf[base + e];
    p = fmaf(rB[base + e] * kf[base + e], r_k[c0 + e], p);
  }
  p += __shfl_xor(p, 1);
  p += __shfl_xor(p, 2);
  p += __shfl_xor(p, 4);
  #pragma unroll
  for (int e = 0; e < 8; ++e) {
    const float yn = (yv[e] - mean) * rstd;
    xxb[base + e] = f2b(fmaf(yn, ln_w[c0 + e], ln_b[c0 + e]) + p * vv[e]);
  }
}

// ---------------------------------------------------------------------------
extern "C" void kernel_launch(void* const* d_in, const int* in_sizes, int n_in,
                              void* d_out, int out_size, void* d_ws, size_t ws_size,
                              hipStream_t stream) {
  const float* x       = (const float*)d_in[0];
  const float* v_first = (const float*)d_in[1];
  const float* state   = (const float*)d_in[2];
  const float* Rw      = (const float*)d_in[3];
  const float* R_bias  = (const float*)d_in[4];
  const float* Kw      = (const float*)d_in[5];
  const float* K_bias  = (const float*)d_in[6];
  const float* Vw      = (const float*)d_in[7];
  const float* V_bias  = (const float*)d_in[8];
  const float* Ow      = (const float*)d_in[9];
  const float* O_bias  = (const float*)d_in[10];
  const float* w0      = (const float*)d_in[11];
  const float* w1      = (const float*)d_in[12];
  const float* w2      = (const float*)d_in[13];
  const float* a0      = (const float*)d_in[14];
  const float* a1      = (const float*)d_in[15];
  const float* a2      = (const float*)d_in[16];
  const float* v0      = (const float*)d_in[17];
  const float* v1      = (const float*)d_in[18];
  const float* v2      = (const float*)d_in[19];
  const float* k_k     = (const float*)d_in[20];
  const float* k_a     = (const float*)d_in[21];
  const float* r_k     = (const float*)d_in[22];
  const float* ln_w    = (const float*)d_in[23];
  const float* ln_b    = (const float*)d_in[24];

  float* ws = (float*)d_ws;
  float* r_buf = ws;                    // 8388608
  float* k_buf = r_buf + 8388608;       // 2097152
  float* v_buf = k_buf + 2097152;       // 2097152
  float* wt    = v_buf + 2097152;       // 8388608 (u -> decay in place)
  float* at    = wt    + 8388608;       // 8388608 (a pre-act -> y after scan)
  float* vt    = at    + 8388608;       // 8388608 (v pre-act -> v_final)
  float* kf    = vt    + 8388608;       // 8388608
  float* aaq   = kf    + 8388608;       // 8388608
  float* bbq   = aaq   + 8388608;       // 8388608
  float* part  = bbq   + 8388608;       // 2048 (gnorm partials)
  // bf16 aliases into dead-at-use regions (all 16B-aligned):
  unsigned short* xb   = (unsigned short*)bbq;               // dead until prep
  unsigned short* RKVb = (unsigned short*)kf;                // 3072x2048 bf16
  unsigned short* hcat = (unsigned short*)(kf + 3200000);    // 4096x160 bf16
  unsigned short* Bcat = (unsigned short*)(kf + 3600000);    // 160x2048 bf16
  unsigned short* w2t  = (unsigned short*)(kf + 3800000);    // 2048x64
  unsigned short* a2t  = (unsigned short*)(kf + 3900000);    // 2048x64
  unsigned short* v2t  = (unsigned short*)(kf + 4000000);    // 2048x32
  unsigned short* Ob   = (unsigned short*)wt;                // after scan
  unsigned short* xxb  = (unsigned short*)aaq;               // after scan

  dim3 blk(256);
  // ---- converts ----
  cvt4_kernel<<<14336, blk, 0, stream>>>(x, Rw, Kw, Vw, xb, RKVb);
  tcvt_kernel<<<dim3(1, 32), blk, 0, stream>>>(w1, Bcat,              2048, 64, 2048);
  tcvt_kernel<<<dim3(1, 32), blk, 0, stream>>>(a1, Bcat + 64 * 2048,  2048, 64, 2048);
  tcvt_kernel<<<dim3(1, 32), blk, 0, stream>>>(v1, Bcat + 128 * 2048, 2048, 32, 2048);
  tcvt_kernel<<<dim3(32, 1), blk, 0, stream>>>(w2, w2t, 64, 2048, 64);
  tcvt_kernel<<<dim3(32, 1), blk, 0, stream>>>(a2, a2t, 64, 2048, 64);
  tcvt_kernel<<<dim3(32, 1), blk, 0, stream>>>(v2, v2t, 32, 2048, 32);
  // ---- low-rank stage 1 (fused, bf16 out, tanh on w-cols) ----
  gemm_mfma<1,2><<<dim3(2, 32), blk, 0, stream>>>(xb, 2048, Bcat, 2048, nullptr,
                                                  hcat, 160, 4096, 160, 2048);
  // ---- merged R|K|V projection ----
  gemm_rkv<<<dim3(24, 32), blk, 0, stream>>>(xb, RKVb, R_bias, K_bias, V_bias,
                                             r_buf, k_buf, v_buf);
  // ---- low-rank stage 2 ----
  gemm_mfma<0,0><<<dim3(16, 32), blk, 0, stream>>>(hcat, 160, w2t, 64, nullptr,
                                                   wt, 2048, 4096, 2048, 64);
  gemm_mfma<0,0><<<dim3(16, 32), blk, 0, stream>>>(hcat + 64, 160, a2t, 64, nullptr,
                                                   at, 2048, 4096, 2048, 64);
  gemm_mfma<0,0><<<dim3(16, 32), blk, 0, stream>>>(hcat + 128, 160, v2t, 32, nullptr,
                                                   vt, 2048, 4096, 2048, 32);
  // ---- elementwise prep ----
  prep_kernel<<<4096, blk, 0, stream>>>(k_buf, v_buf, wt, at, vt, v_first,
                                        w0, a0, v0, k_k, k_a, kf, aaq, bbq);
  // ---- recurrent scan (row-parallel, XCD-swizzled; y reuses `at`) ----
  float* ybuf = at;
  scan_kernel<<<512, blk, 0, stream>>>(r_buf, wt, kf, vt, aaq, bbq, state, ybuf);
  // ---- O weight convert (wt dead after scan) ----
  cvt_bf16<<<4096, blk, 0, stream>>>(Ow, Ob, 1048576);
  // ---- group norm (two passes) + bonus -> bf16 xx ----
  gsum_kernel<<<1024, blk, 0, stream>>>(ybuf, part);
  gapply_kernel<<<4096, blk, 0, stream>>>(ybuf, r_buf, kf, vt, part, r_k,
                                          ln_w, ln_b, xxb);
  // ---- output projection ----
  gemm_mfma<0,0><<<dim3(16, 32), blk, 0, stream>>>(xxb, 2048, Ob, 2048, O_bias,
                                                   (float*)d_out, 2048, 4096, 2048, 2048);
}